// Round 13
// baseline (362.962 us; speedup 1.0000x reference)
//
#include <hip/hip_runtime.h>
#include <hip/hip_bf16.h>
#include <cstdint>

#define K_DIM 768
#define M_DIM 3072
#define BS_TOTAL 16384  // B * S
#define KT 12           // K tiles of 64
#define BM 256
#define BN 384

typedef __attribute__((ext_vector_type(4))) float f32x4;
typedef __attribute__((ext_vector_type(8))) short bf16x8;
typedef __attribute__((ext_vector_type(4))) unsigned short u16x4;
typedef __attribute__((ext_vector_type(4))) float fv4;

typedef unsigned int u32_g __attribute__((address_space(1)));
typedef unsigned int u32_l __attribute__((address_space(3)));

static __device__ __forceinline__ void async_load16(const void* g, void* l) {
    __builtin_amdgcn_global_load_lds((const u32_g*)g, (u32_l*)l, 16, 0, 0);
}

#define BAR() __builtin_amdgcn_s_barrier()
#define SCHEDB() __builtin_amdgcn_sched_barrier(0)

static __device__ __forceinline__ unsigned short f2bf(float f) {
    unsigned u = __builtin_bit_cast(unsigned, f);
    u += 0x7fffu + ((u >> 16) & 1u);   // RNE
    return (unsigned short)(u >> 16);
}

// Merged prep: blocks [0, M_DIM) densify W rows; rest convert x to bf16.
__global__ void prep_kernel(const float* __restrict__ values,
                            const int* __restrict__ row_offsets,
                            const int* __restrict__ column_indices,
                            unsigned short* __restrict__ Wb,
                            const float* __restrict__ x,
                            unsigned short* __restrict__ xb, int n4) {
    const int b = blockIdx.x;
    const int t = threadIdx.x;
    if (b < M_DIM) {
        const int r = b;
        unsigned int* wrow32 = (unsigned int*)(Wb + (size_t)r * K_DIM);
        for (int i = t; i < K_DIM / 2; i += 256) wrow32[i] = 0u;
        __syncthreads();
        const int start = row_offsets[r], end = row_offsets[r + 1];
        unsigned short* wrow = Wb + (size_t)r * K_DIM;
        for (int i = start + t; i < end; i += 256)
            wrow[column_indices[i]] = f2bf(values[i]);
    } else {
        const int i = (b - M_DIM) * 256 + t;
        if (i < n4) {
            fv4 v = ((const fv4*)x)[i];
            u16x4 o;
            o[0] = f2bf(v[0]); o[1] = f2bf(v[1]); o[2] = f2bf(v[2]); o[3] = f2bf(v[3]);
            ((u16x4*)xb)[i] = o;
        }
    }
}

// ---- 256x384 tile, BK=64, 12 waves (2Mx6N, wave-tile 128x64 == R2's verified
// per-wave structure), dbuf LDS = exactly 160 KiB. Grid = 64x8 = 512 blocks =
// EXACTLY 2 generations (one boundary eliminated) at 3 waves/SIMD (vs R12's 2).
// R12's coarsened 3-barrier schedule ported unchanged; counted vmcnt stays
// exact despite ragged A-staging because every wait's TRAILING in-flight count
// is the uniform B-stage count (4/wave). Same swizzle involution, L2 mapping,
// m89 C/D layout.

#define STAGE_A(buf, t, half)                                                   \
    { _Pragma("unroll") for (int c = 0; c < 2; ++c) {                           \
        const int u = c * 768 + tid;                                            \
        if (u < 1024) {                                                         \
            const int row = (half) * 128 + (u >> 3);                            \
            const int gs = (u & 7) ^ (row & 7);                                 \
            async_load16(X + (size_t)(row0 + row) * K_DIM + (t) * 64 + gs * 8,  \
                         &smA[buf][row * 64 + (u & 7) * 8]); } } }

#define STAGE_B(buf, t, half)                                                   \
    { _Pragma("unroll") for (int c = 0; c < 2; ++c) {                           \
        const int u = c * 768 + tid;                                            \
        const int row = (half) * 192 + (u >> 3);                                \
        const int gs = (u & 7) ^ (row & 7);                                     \
        async_load16(W + (size_t)(col0 + row) * K_DIM + (t) * 64 + gs * 8,      \
                     &smB[buf][row * 64 + (u & 7) * 8]); } }

#define LDA(buf, mh)                                                            \
    { _Pragma("unroll") for (int mi = 0; mi < 4; ++mi) {                        \
        const int row = wm * 128 + (mh) * 64 + mi * 16 + fr;                    \
        const int sw = (row & 7) << 3;                                          \
        aq[mi][0] = *(const bf16x8*)&smA[buf][row * 64 + ((kq * 8) ^ sw)];      \
        aq[mi][1] = *(const bf16x8*)&smA[buf][row * 64 + ((32 + kq * 8) ^ sw)]; } }

#define LDB(buf, nh, breg)                                                      \
    { _Pragma("unroll") for (int ni = 0; ni < 2; ++ni) {                        \
        const int row = wn * 64 + (nh) * 32 + ni * 16 + fr;                     \
        const int sw = (row & 7) << 3;                                          \
        breg[ni][0] = *(const bf16x8*)&smB[buf][row * 64 + ((kq * 8) ^ sw)];    \
        breg[ni][1] = *(const bf16x8*)&smB[buf][row * 64 + ((32 + kq * 8) ^ sw)]; } }

#define MFMA16(mh, nh, breg)                                                    \
    { _Pragma("unroll") for (int mi = 0; mi < 4; ++mi)                          \
      _Pragma("unroll") for (int ni = 0; ni < 2; ++ni) {                        \
        acc[(mh)*4+mi][(nh)*2+ni] = __builtin_amdgcn_mfma_f32_16x16x32_bf16(    \
            aq[mi][0], breg[ni][0], acc[(mh)*4+mi][(nh)*2+ni], 0, 0, 0);        \
        acc[(mh)*4+mi][(nh)*2+ni] = __builtin_amdgcn_mfma_f32_16x16x32_bf16(    \
            aq[mi][1], breg[ni][1], acc[(mh)*4+mi][(nh)*2+ni], 0, 0, 0); } }

__global__ __launch_bounds__(768, 1) void gemm_kernel(
    const unsigned short* __restrict__ X,
    const unsigned short* __restrict__ W,
    const float* __restrict__ bias,
    float* __restrict__ out) {
    __shared__ __align__(16) unsigned short smA[2][256 * 64];  //  64 KiB
    __shared__ __align__(16) unsigned short smB[2][384 * 64];  //  96 KiB

    // L2-aware mapping: per XCD 8 fixed row-panels (X slice 3 MB), bx outer 0..7.
    const int bid = blockIdx.x;           // 0..511
    const int xcd = bid & 7;
    const int j   = bid >> 3;             // 0..63
    const int by  = xcd * 8 + (j & 7);    // 0..63
    const int bx  = j >> 3;               // 0..7
    const int row0 = by * BM;
    const int col0 = bx * BN;

    const int tid  = threadIdx.x;
    const int lane = tid & 63;
    const int wave = tid >> 6;            // 0..11
    const int wm = wave / 6;              // 0..1 -> A rows wm*128..+127
    const int wn = wave % 6;              // 0..5 -> B rows wn*64..+63
    const int fr = lane & 15;
    const int kq = lane >> 4;             // 0..3

    f32x4 acc[8][4] = {};
    bf16x8 aq[4][2], b0[2][2], b1[2][2];

    // prologue: tile 0 fully + B of tile 1
    STAGE_A(0, 0, 0); STAGE_A(0, 0, 1);
    STAGE_B(0, 0, 0); STAGE_B(0, 0, 1);
    STAGE_B(1, 1, 0); STAGE_B(1, 1, 1);
    // drains A(0)+B(0) (ragged A count irrelevant: trailing = B(1) = 4/wave)
    asm volatile("s_waitcnt vmcnt(4)" ::: "memory");
    SCHEDB();
    BAR();

    for (int t = 0; t < KT; ++t) {
        const int buf = t & 1, nbuf = buf ^ 1;

        // ---- cluster A: quadrants (0,0) + (0,1) ----
        LDA(buf, 0);
        LDB(buf, 0, b0);
        LDB(buf, 1, b1);
        if (t + 1 < KT) { STAGE_A(nbuf, t + 1, 0); STAGE_A(nbuf, t + 1, 1); }
        BAR();                                   // BAR1
        __builtin_amdgcn_s_setprio(1);
        MFMA16(0, 0, b0);
        MFMA16(0, 1, b1);
        __builtin_amdgcn_s_setprio(0);

        // ---- cluster B: quadrants (1,1) + (1,0) ----
        LDA(buf, 1);
        BAR();                                   // BAR2: b0/b1 consumed by all
        if (t + 2 < KT) { STAGE_B(buf, t + 2, 0); STAGE_B(buf, t + 2, 1); }
        __builtin_amdgcn_s_setprio(1);
        MFMA16(1, 1, b1);
        MFMA16(1, 0, b0);
        __builtin_amdgcn_s_setprio(0);

        // counted end-of-tile wait: drains B(t+1)+A(t+1), keeps B(t+2)=4 flying
        if (t + 2 < KT)      { asm volatile("s_waitcnt vmcnt(4)" ::: "memory"); SCHEDB(); BAR(); }
        else if (t + 1 < KT) { asm volatile("s_waitcnt vmcnt(0)" ::: "memory"); SCHEDB(); BAR(); }
    }

    // epilogue: frag row = kq*4 + j, col = fr (m89-verified C/D layout)
    float bv[4];
#pragma unroll
    for (int ni = 0; ni < 4; ++ni) bv[ni] = bias[col0 + wn * 64 + ni * 16 + fr];

    const int orow0 = row0 + wm * 128 + kq * 4;
#pragma unroll
    for (int mi = 0; mi < 8; ++mi)
#pragma unroll
        for (int jj = 0; jj < 4; ++jj) {
            float* op = out + (size_t)(orow0 + mi * 16 + jj) * M_DIM + col0 + wn * 64 + fr;
#pragma unroll
            for (int ni = 0; ni < 4; ++ni)
                op[ni * 16] = acc[mi][ni][jj] + bv[ni];
        }
}

extern "C" void kernel_launch(void* const* d_in, const int* in_sizes, int n_in,
                              void* d_out, int out_size, void* d_ws, size_t ws_size,
                              hipStream_t stream) {
    const float* values         = (const float*)d_in[0];
    const float* bias           = (const float*)d_in[1];
    const float* x              = (const float*)d_in[2];
    const int*   row_offsets    = (const int*)d_in[4];
    const int*   column_indices = (const int*)d_in[5];

    unsigned short* Wb = (unsigned short*)d_ws;
    unsigned short* Xb = (unsigned short*)((char*)d_ws + (size_t)M_DIM * K_DIM * 2);

    const int n4 = BS_TOTAL * K_DIM / 4;
    const int prep_blocks = M_DIM + (n4 + 255) / 256;
    prep_kernel<<<prep_blocks, 256, 0, stream>>>(values, row_offsets, column_indices,
                                                 Wb, x, Xb, n4);

    const int grid = (BS_TOTAL / BM) * (M_DIM / BN);  // 64 * 8 = 512
    gemm_kernel<<<grid, 768, 0, stream>>>(Xb, Wb, bias, (float*)d_out);
}

// Round 14
// 182.274 us; speedup vs baseline: 1.9913x; 1.9913x over previous
//
#include <hip/hip_runtime.h>
#include <hip/hip_bf16.h>
#include <cstdint>

#define K_DIM 768
#define M_DIM 3072
#define BS_TOTAL 16384  // B * S
#define KT 12           // K tiles of 64

typedef __attribute__((ext_vector_type(4))) float f32x4;
typedef __attribute__((ext_vector_type(8))) short bf16x8;
typedef __attribute__((ext_vector_type(2))) unsigned int u32x2;
typedef __attribute__((ext_vector_type(4))) float fv4;

typedef unsigned int u32_g __attribute__((address_space(1)));
typedef unsigned int u32_l __attribute__((address_space(3)));

static __device__ __forceinline__ void async_load16(const void* g, void* l) {
    __builtin_amdgcn_global_load_lds((const u32_g*)g, (u32_l*)l, 16, 0, 0);
}

#define BAR() __builtin_amdgcn_s_barrier()
#define SCHEDB() __builtin_amdgcn_sched_barrier(0)

static __device__ __forceinline__ unsigned short f2bf(float f) {
    unsigned u = __builtin_bit_cast(unsigned, f);
    u += 0x7fffu + ((u >> 16) & 1u);   // RNE
    return (unsigned short)(u >> 16);
}

// pack two fp32 -> one u32 of 2 bf16 (RNE both)
static __device__ __forceinline__ unsigned int pack2bf(float a, float b) {
    unsigned ua = __builtin_bit_cast(unsigned, a);
    unsigned ub = __builtin_bit_cast(unsigned, b);
    ua += 0x7fffu + ((ua >> 16) & 1u);
    ub += 0x7fffu + ((ub >> 16) & 1u);
    return (ua >> 16) | (ub & 0xffff0000u);
}

// prep = densify only (x conversion is fused into the GEMM's A-staging)
__global__ void prep_kernel(const float* __restrict__ values,
                            const int* __restrict__ row_offsets,
                            const int* __restrict__ column_indices,
                            unsigned short* __restrict__ Wb) {
    const int r = blockIdx.x;
    const int t = threadIdx.x;
    unsigned int* wrow32 = (unsigned int*)(Wb + (size_t)r * K_DIM);
    for (int i = t; i < K_DIM / 2; i += 256) wrow32[i] = 0u;
    __syncthreads();
    const int start = row_offsets[r], end = row_offsets[r + 1];
    unsigned short* wrow = Wb + (size_t)r * K_DIM;
    for (int i = start + t; i < end; i += 256)
        wrow[column_indices[i]] = f2bf(values[i]);
}

// ---- R12 core (best: 102.7 us) with x-convert FUSED into A-staging ----
// 256x256, BK=64, 8 waves 2Mx4N, dbuf 128 KiB, coarsened 3-barrier K-tile,
// counted vmcnt, R8 L2 mapping, m89 C/D layout.
// A is reg-staged: 8x global_load_dwordx4 (fp32 x) issued in cluster A for
// tile t+1; end-of-tile vmcnt(4) drains them (FIFO: [B(t+1) 4, A 8, B(t+2) 4]
// -> trailing 4 = B(t+2) stays in flight); then RNE-pack + 8 swizzled
// ds_write_b64 + lgkmcnt(0) + BAR. Swizzle now applied on the WRITE side
// (reg-staged, no gload_lds constraint for A); read side unchanged.

// u = c*512 + tid; row = u>>4 (0..255), seg = u&15 (4-float group in row)
#define ALOAD(t)                                                                \
    { _Pragma("unroll") for (int c = 0; c < 8; ++c) {                           \
        const int u = c * 512 + tid;                                            \
        const int row = u >> 4, seg = u & 15;                                   \
        fa[c] = *(const fv4*)(X32 + (size_t)(row0 + row) * K_DIM                \
                              + (t) * 64 + seg * 4); } }

#define AWRITE(buf)                                                             \
    { _Pragma("unroll") for (int c = 0; c < 8; ++c) {                           \
        const int u = c * 512 + tid;                                            \
        const int row = u >> 4, seg = u & 15;                                   \
        const int off = row * 64 + (((seg >> 1) ^ (row & 7)) * 8)               \
                        + (seg & 1) * 4;                                        \
        u32x2 pk; pk[0] = pack2bf(fa[c][0], fa[c][1]);                          \
        pk[1] = pack2bf(fa[c][2], fa[c][3]);                                    \
        *(u32x2*)&smA[buf][off] = pk; } }

#define STAGE_B(buf, t, half)                                                   \
    { _Pragma("unroll") for (int c = 0; c < 2; ++c) {                           \
        const int u = c * 512 + tid;                                            \
        const int row = (half) * 128 + (u >> 3);                                \
        const int gs = (u & 7) ^ (row & 7);                                     \
        async_load16(W + (size_t)(col0 + row) * K_DIM + (t) * 64 + gs * 8,      \
                     &smB[buf][row * 64 + (u & 7) * 8]); } }

#define LDA(buf, mh)                                                            \
    { _Pragma("unroll") for (int mi = 0; mi < 4; ++mi) {                        \
        const int row = wm * 128 + (mh) * 64 + mi * 16 + fr;                    \
        const int sw = (row & 7) << 3;                                          \
        aq[mi][0] = *(const bf16x8*)&smA[buf][row * 64 + ((kq * 8) ^ sw)];      \
        aq[mi][1] = *(const bf16x8*)&smA[buf][row * 64 + ((32 + kq * 8) ^ sw)]; } }

#define LDB(buf, nh, breg)                                                      \
    { _Pragma("unroll") for (int ni = 0; ni < 2; ++ni) {                        \
        const int row = wn * 64 + (nh) * 32 + ni * 16 + fr;                     \
        const int sw = (row & 7) << 3;                                          \
        breg[ni][0] = *(const bf16x8*)&smB[buf][row * 64 + ((kq * 8) ^ sw)];    \
        breg[ni][1] = *(const bf16x8*)&smB[buf][row * 64 + ((32 + kq * 8) ^ sw)]; } }

#define MFMA16(mh, nh, breg)                                                    \
    { _Pragma("unroll") for (int mi = 0; mi < 4; ++mi)                          \
      _Pragma("unroll") for (int ni = 0; ni < 2; ++ni) {                        \
        acc[(mh)*4+mi][(nh)*2+ni] = __builtin_amdgcn_mfma_f32_16x16x32_bf16(    \
            aq[mi][0], breg[ni][0], acc[(mh)*4+mi][(nh)*2+ni], 0, 0, 0);        \
        acc[(mh)*4+mi][(nh)*2+ni] = __builtin_amdgcn_mfma_f32_16x16x32_bf16(    \
            aq[mi][1], breg[ni][1], acc[(mh)*4+mi][(nh)*2+ni], 0, 0, 0); } }

__global__ __launch_bounds__(512, 2) void gemm_kernel(
    const float* __restrict__ X32,
    const unsigned short* __restrict__ W,
    const float* __restrict__ bias,
    float* __restrict__ out) {
    __shared__ __align__(16) unsigned short smA[2][256 * 64];  // 32 KiB x2
    __shared__ __align__(16) unsigned short smB[2][256 * 64];  // 32 KiB x2

    // R8's L2-aware mapping: per XCD 8 fixed row-panels, bx outer.
    const int bid = blockIdx.x;           // 0..767
    const int xcd = bid & 7;
    const int j   = bid >> 3;             // 0..95
    const int by  = xcd * 8 + (j & 7);    // 0..63
    const int bx  = j >> 3;               // 0..11
    const int row0 = by * 256;
    const int col0 = bx * 256;

    const int tid  = threadIdx.x;
    const int lane = tid & 63;
    const int wave = tid >> 6;
    const int wm = wave >> 2;   // 0..1 -> A rows wm*128..+127
    const int wn = wave & 3;    // 0..3 -> B rows wn*64..+63
    const int fr = lane & 15;
    const int kq = lane >> 4;   // 0..3

    f32x4 acc[8][4] = {};
    bf16x8 aq[4][2], b0[2][2], b1[2][2];
    fv4 fa[8];

    // prologue: A-loads(0), B(0), B(1); vmcnt(4) drains A+B(0), leaves B(1)
    ALOAD(0);
    STAGE_B(0, 0, 0); STAGE_B(0, 0, 1);
    STAGE_B(1, 1, 0); STAGE_B(1, 1, 1);
    asm volatile("s_waitcnt vmcnt(4)" ::: "memory");
    SCHEDB();
    AWRITE(0);
    asm volatile("s_waitcnt lgkmcnt(0)" ::: "memory");
    SCHEDB();
    BAR();

    for (int t = 0; t < KT; ++t) {
        const int buf = t & 1, nbuf = buf ^ 1;

        // ---- cluster A: quadrants (0,0) + (0,1); issue A-loads for t+1 ----
        LDA(buf, 0);
        LDB(buf, 0, b0);
        LDB(buf, 1, b1);
        if (t + 1 < KT) ALOAD(t + 1);
        BAR();                                   // BAR1: tile t buffers ready
        __builtin_amdgcn_s_setprio(1);
        MFMA16(0, 0, b0);
        MFMA16(0, 1, b1);
        __builtin_amdgcn_s_setprio(0);

        // ---- cluster B: quadrants (1,1) + (1,0) ----
        LDA(buf, 1);
        BAR();                                   // BAR2: b0/b1 consumed by all
        if (t + 2 < KT) { STAGE_B(buf, t + 2, 0); STAGE_B(buf, t + 2, 1); }
        __builtin_amdgcn_s_setprio(1);
        MFMA16(1, 1, b1);
        MFMA16(1, 0, b0);
        __builtin_amdgcn_s_setprio(0);

        // end of tile: drain A-loads(t+1)+B(t+1), keep B(t+2) flying;
        // then write smA[nbuf] and barrier into tile t+1.
        if (t + 1 < KT) {
            if (t + 2 < KT) { asm volatile("s_waitcnt vmcnt(4)" ::: "memory"); }
            else            { asm volatile("s_waitcnt vmcnt(0)" ::: "memory"); }
            SCHEDB();
            AWRITE(nbuf);
            asm volatile("s_waitcnt lgkmcnt(0)" ::: "memory");
            SCHEDB();
            BAR();
        }
    }

    // epilogue: frag row = kq*4 + j, col = fr (m89-verified C/D layout)
    float bv[4];
#pragma unroll
    for (int ni = 0; ni < 4; ++ni) bv[ni] = bias[col0 + wn * 64 + ni * 16 + fr];

    const int orow0 = row0 + wm * 128 + kq * 4;
#pragma unroll
    for (int mi = 0; mi < 8; ++mi)
#pragma unroll
        for (int jj = 0; jj < 4; ++jj) {
            float* op = out + (size_t)(orow0 + mi * 16 + jj) * M_DIM + col0 + wn * 64 + fr;
#pragma unroll
            for (int ni = 0; ni < 4; ++ni)
                op[ni * 16] = acc[mi][ni][jj] + bv[ni];
        }
}

extern "C" void kernel_launch(void* const* d_in, const int* in_sizes, int n_in,
                              void* d_out, int out_size, void* d_ws, size_t ws_size,
                              hipStream_t stream) {
    const float* values         = (const float*)d_in[0];
    const float* bias           = (const float*)d_in[1];
    const float* x              = (const float*)d_in[2];
    const int*   row_offsets    = (const int*)d_in[4];
    const int*   column_indices = (const int*)d_in[5];

    unsigned short* Wb = (unsigned short*)d_ws;

    prep_kernel<<<M_DIM, 256, 0, stream>>>(values, row_offsets, column_indices, Wb);

    const int grid = (BS_TOTAL / 256) * (M_DIM / 256);  // 64 * 12 = 768
    gemm_kernel<<<grid, 512, 0, stream>>>(x, Wb, bias, (float*)d_out);
}

// Round 15
// 102.536 us; speedup vs baseline: 3.5398x; 1.7777x over previous
//
#include <hip/hip_runtime.h>
#include <hip/hip_bf16.h>
#include <cstdint>

#define K_DIM 768
#define M_DIM 3072
#define BS_TOTAL 16384  // B * S
#define KT 12           // K tiles of 64

typedef __attribute__((ext_vector_type(4))) float f32x4;
typedef __attribute__((ext_vector_type(8))) short bf16x8;
typedef __attribute__((ext_vector_type(4))) unsigned short u16x4;
typedef __attribute__((ext_vector_type(4))) float fv4;

typedef unsigned int u32_g __attribute__((address_space(1)));
typedef unsigned int u32_l __attribute__((address_space(3)));

static __device__ __forceinline__ void async_load16(const void* g, void* l) {
    __builtin_amdgcn_global_load_lds((const u32_g*)g, (u32_l*)l, 16, 0, 0);
}

#define BAR() __builtin_amdgcn_s_barrier()
#define SCHEDB() __builtin_amdgcn_sched_barrier(0)

static __device__ __forceinline__ unsigned short f2bf(float f) {
    unsigned u = __builtin_bit_cast(unsigned, f);
    u += 0x7fffu + ((u >> 16) & 1u);   // RNE
    return (unsigned short)(u >> 16);
}

// Merged prep: blocks [0, M_DIM) densify W rows; rest convert x to bf16.
__global__ void prep_kernel(const float* __restrict__ values,
                            const int* __restrict__ row_offsets,
                            const int* __restrict__ column_indices,
                            unsigned short* __restrict__ Wb,
                            const float* __restrict__ x,
                            unsigned short* __restrict__ xb, int n4) {
    const int b = blockIdx.x;
    const int t = threadIdx.x;
    if (b < M_DIM) {
        const int r = b;
        unsigned int* wrow32 = (unsigned int*)(Wb + (size_t)r * K_DIM);
        for (int i = t; i < K_DIM / 2; i += 256) wrow32[i] = 0u;
        __syncthreads();
        const int start = row_offsets[r], end = row_offsets[r + 1];
        unsigned short* wrow = Wb + (size_t)r * K_DIM;
        for (int i = start + t; i < end; i += 256)
            wrow[column_indices[i]] = f2bf(values[i]);
    } else {
        const int i = (b - M_DIM) * 256 + t;
        if (i < n4) {
            fv4 v = ((const fv4*)x)[i];
            u16x4 o;
            o[0] = f2bf(v[0]); o[1] = f2bf(v[1]); o[2] = f2bf(v[2]); o[3] = f2bf(v[3]);
            ((u16x4*)xb)[i] = o;
        }
    }
}

// ---- R12 core, verbatim (best measured: 102.7 us total) ----
// 256x256, BK=64, 8 waves 2Mx4N (wave-tile 128x64), dbuf 128 KiB, coarsened
// 3-barrier K-tile schedule, counted vmcnt (never 0 steady-state), XOR swizzle
// involution on both sides, R8 L2-aware block mapping, m89 C/D layout.

#define STAGE_A(buf, t, half)                                                   \
    { _Pragma("unroll") for (int c = 0; c < 2; ++c) {                           \
        const int u = c * 512 + tid;                                            \
        const int row = (half) * 128 + (u >> 3);                                \
        const int gs = (u & 7) ^ (row & 7);                                     \
        async_load16(X + (size_t)(row0 + row) * K_DIM + (t) * 64 + gs * 8,      \
                     &sm[buf][0][row * 64 + (u & 7) * 8]); } }

#define STAGE_B(buf, t, half)                                                   \
    { _Pragma("unroll") for (int c = 0; c < 2; ++c) {                           \
        const int u = c * 512 + tid;                                            \
        const int row = (half) * 128 + (u >> 3);                                \
        const int gs = (u & 7) ^ (row & 7);                                     \
        async_load16(W + (size_t)(col0 + row) * K_DIM + (t) * 64 + gs * 8,      \
                     &sm[buf][1][row * 64 + (u & 7) * 8]); } }

#define LDA(buf, mh)                                                            \
    { _Pragma("unroll") for (int mi = 0; mi < 4; ++mi) {                        \
        const int row = wm * 128 + (mh) * 64 + mi * 16 + fr;                    \
        const int sw = (row & 7) << 3;                                          \
        aq[mi][0] = *(const bf16x8*)&sm[buf][0][row * 64 + ((kq * 8) ^ sw)];    \
        aq[mi][1] = *(const bf16x8*)&sm[buf][0][row * 64 + ((32 + kq * 8) ^ sw)]; } }

#define LDB(buf, nh, breg)                                                      \
    { _Pragma("unroll") for (int ni = 0; ni < 2; ++ni) {                        \
        const int row = wn * 64 + (nh) * 32 + ni * 16 + fr;                     \
        const int sw = (row & 7) << 3;                                          \
        breg[ni][0] = *(const bf16x8*)&sm[buf][1][row * 64 + ((kq * 8) ^ sw)];  \
        breg[ni][1] = *(const bf16x8*)&sm[buf][1][row * 64 + ((32 + kq * 8) ^ sw)]; } }

#define MFMA16(mh, nh, breg)                                                    \
    { _Pragma("unroll") for (int mi = 0; mi < 4; ++mi)                          \
      _Pragma("unroll") for (int ni = 0; ni < 2; ++ni) {                        \
        acc[(mh)*4+mi][(nh)*2+ni] = __builtin_amdgcn_mfma_f32_16x16x32_bf16(    \
            aq[mi][0], breg[ni][0], acc[(mh)*4+mi][(nh)*2+ni], 0, 0, 0);        \
        acc[(mh)*4+mi][(nh)*2+ni] = __builtin_amdgcn_mfma_f32_16x16x32_bf16(    \
            aq[mi][1], breg[ni][1], acc[(mh)*4+mi][(nh)*2+ni], 0, 0, 0); } }

__global__ __launch_bounds__(512, 2) void gemm_kernel(
    const unsigned short* __restrict__ X,
    const unsigned short* __restrict__ W,
    const float* __restrict__ bias,
    float* __restrict__ out) {
    __shared__ __align__(16) unsigned short sm[2][2][256 * 64];  // 128 KiB

    // R8's L2-aware mapping: per XCD 8 fixed row-panels (X slice 3 MB), bx outer.
    const int bid = blockIdx.x;           // 0..767
    const int xcd = bid & 7;
    const int j   = bid >> 3;             // 0..95
    const int by  = xcd * 8 + (j & 7);    // 0..63
    const int bx  = j >> 3;               // 0..11
    const int row0 = by * 256;
    const int col0 = bx * 256;

    const int tid  = threadIdx.x;
    const int lane = tid & 63;
    const int wave = tid >> 6;
    const int wm = wave >> 2;   // 0..1 -> A rows wm*128..+127
    const int wn = wave & 3;    // 0..3 -> B rows wn*64..+63
    const int fr = lane & 15;
    const int kq = lane >> 4;   // 0..3

    f32x4 acc[8][4] = {};
    bf16x8 aq[4][2], b0[2][2], b1[2][2];

    // prologue: tile 0 fully + B of tile 1
    STAGE_A(0, 0, 0); STAGE_A(0, 0, 1);
    STAGE_B(0, 0, 0); STAGE_B(0, 0, 1);
    STAGE_B(1, 1, 0); STAGE_B(1, 1, 1);
    asm volatile("s_waitcnt vmcnt(4)" ::: "memory");  // tile 0 complete; B(1) flying
    SCHEDB();
    BAR();

    for (int t = 0; t < KT; ++t) {
        const int buf = t & 1, nbuf = buf ^ 1;

        // ---- cluster A: quadrants (0,0) + (0,1) ----
        LDA(buf, 0);
        LDB(buf, 0, b0);
        LDB(buf, 1, b1);
        if (t + 1 < KT) { STAGE_A(nbuf, t + 1, 0); STAGE_A(nbuf, t + 1, 1); }
        BAR();                                   // BAR1: tile t's buffers ready
        __builtin_amdgcn_s_setprio(1);
        MFMA16(0, 0, b0);
        MFMA16(0, 1, b1);
        __builtin_amdgcn_s_setprio(0);

        // ---- cluster B: quadrants (1,1) + (1,0) ----
        LDA(buf, 1);                             // overlaps cluster-A pipe drain
        BAR();                                   // BAR2: all waves consumed b0/b1
        if (t + 2 < KT) { STAGE_B(buf, t + 2, 0); STAGE_B(buf, t + 2, 1); }
        __builtin_amdgcn_s_setprio(1);
        MFMA16(1, 1, b1);
        MFMA16(1, 0, b0);
        __builtin_amdgcn_s_setprio(0);

        // counted end-of-tile wait: drains B(t+1)+A(t+1), keeps B(t+2) flying
        if (t + 2 < KT)      { asm volatile("s_waitcnt vmcnt(4)" ::: "memory"); SCHEDB(); BAR(); }
        else if (t + 1 < KT) { asm volatile("s_waitcnt vmcnt(0)" ::: "memory"); SCHEDB(); BAR(); }
    }

    // epilogue: frag row = kq*4 + j, col = fr (m89-verified C/D layout)
    float bv[4];
#pragma unroll
    for (int ni = 0; ni < 4; ++ni) bv[ni] = bias[col0 + wn * 64 + ni * 16 + fr];

    const int orow0 = row0 + wm * 128 + kq * 4;
#pragma unroll
    for (int mi = 0; mi < 8; ++mi)
#pragma unroll
        for (int jj = 0; jj < 4; ++jj) {
            float* op = out + (size_t)(orow0 + mi * 16 + jj) * M_DIM + col0 + wn * 64 + fr;
#pragma unroll
            for (int ni = 0; ni < 4; ++ni)
                op[ni * 16] = acc[mi][ni][jj] + bv[ni];
        }
}

extern "C" void kernel_launch(void* const* d_in, const int* in_sizes, int n_in,
                              void* d_out, int out_size, void* d_ws, size_t ws_size,
                              hipStream_t stream) {
    const float* values         = (const float*)d_in[0];
    const float* bias           = (const float*)d_in[1];
    const float* x              = (const float*)d_in[2];
    const int*   row_offsets    = (const int*)d_in[4];
    const int*   column_indices = (const int*)d_in[5];

    unsigned short* Wb = (unsigned short*)d_ws;
    unsigned short* Xb = (unsigned short*)((char*)d_ws + (size_t)M_DIM * K_DIM * 2);

    const int n4 = BS_TOTAL * K_DIM / 4;
    const int prep_blocks = M_DIM + (n4 + 255) / 256;
    prep_kernel<<<prep_blocks, 256, 0, stream>>>(values, row_offsets, column_indices,
                                                 Wb, x, Xb, n4);

    const int grid = (BS_TOTAL / 256) * (M_DIM / 256);  // 64 * 12 = 768
    gemm_kernel<<<grid, 512, 0, stream>>>(Xb, Wb, bias, (float*)d_out);
}